// Round 1
// baseline (80.699 us; speedup 1.0000x reference)
//
#include <hip/hip_runtime.h>

// KspaceFillNeighbourLayer: temporal clipped box-filter sums (radii 0,1,2,4)
// over T=30 frames + masked blend.
// Layout: k,mask = (n,2,T,H,W) f32; out = (n,4,2,T,H,W) f32.
// One thread per (n,c,h,w) column: prefix sums over T in registers,
// 120 coalesced stores per thread. Memory-bound (~378 MB traffic).

#define T_FRAMES 30

__global__ __launch_bounds__(256) void kfill_kernel(
    const float* __restrict__ k, const float* __restrict__ mask,
    float* __restrict__ out, int ncol, int P)
{
    int tid = blockIdx.x * blockDim.x + threadIdx.x;
    int total = ncol * P;
    if (tid >= total) return;

    int col  = tid / P;          // col = n*2 + c
    int pix  = tid - col * P;
    int nidx = col >> 1;
    int c    = col & 1;

    const size_t inBase = (size_t)col * T_FRAMES * P + (size_t)pix;

    // Prefix sums over the temporal axis, kept in registers (static indexing).
    float csK[T_FRAMES + 1], csM[T_FRAMES + 1];
    csK[0] = 0.0f; csM[0] = 0.0f;
#pragma unroll
    for (int t = 0; t < T_FRAMES; ++t) {
        csK[t + 1] = csK[t] + k[inBase + (size_t)t * P];
        csM[t + 1] = csM[t] + mask[inBase + (size_t)t * P];
    }

    const size_t outColBase = (size_t)(nidx * 8 + c) * T_FRAMES * P + (size_t)pix;

    const int FD[4] = {0, 1, 2, 4};
#pragma unroll
    for (int f = 0; f < 4; ++f) {
        const int d = FD[f];
        const size_t fBase = outColBase + (size_t)f * 2 * T_FRAMES * P;
#pragma unroll
        for (int t = 0; t < T_FRAMES; ++t) {
            int hi = t + d + 1; if (hi > T_FRAMES) hi = T_FRAMES;
            int lo = t - d;     if (lo < 0)        lo = 0;
            float ks = csK[hi] - csK[lo];
            float ms = csM[hi] - csM[lo];
            float res = ks / fmaxf(ms, 1.0f);
            // Recover per-frame k and mask from the prefix sums.
            // csM entries are exact integers -> mv is exactly 0.0 or 1.0.
            float kv = csK[t + 1] - csK[t];
            float mv = csM[t + 1] - csM[t];
            out[fBase + (size_t)t * P] = (1.0f - mv) * res + mv * kv;
        }
    }
}

extern "C" void kernel_launch(void* const* d_in, const int* in_sizes, int n_in,
                              void* d_out, int out_size, void* d_ws, size_t ws_size,
                              hipStream_t stream) {
    const float* k    = (const float*)d_in[0];
    const float* mask = (const float*)d_in[1];
    float* out = (float*)d_out;

    const int P = 256 * 256;                       // H*W
    const int ncol = in_sizes[0] / (T_FRAMES * P); // n*2
    const int total = ncol * P;

    const int block = 256;
    const int grid = (total + block - 1) / block;
    kfill_kernel<<<grid, block, 0, stream>>>(k, mask, out, ncol, P);
}